// Round 1
// baseline (10697.889 us; speedup 1.0000x reference)
//
#include <hip/hip_runtime.h>
#include <math.h>

// Problem constants
#define BB 2
#define TT 1024
#define DD 1024
#define HH 16
#define DHD 64
#define HID 4096
#define LL 8
#define VV 32000

// ---------------------------------------------------------------------------
// Embedding: x[b,t,:] = emb[idx[b,t],:] + pos[t,:]
// grid = B*T blocks, 256 threads, float4
// ---------------------------------------------------------------------------
__global__ __launch_bounds__(256)
void embed_k(const int* __restrict__ idx, const float* __restrict__ emb,
             const float* __restrict__ pos, float* __restrict__ x)
{
    int row = blockIdx.x;              // b*T + t
    int t = row & (TT - 1);
    int tok = idx[row];
    const float4* e4 = (const float4*)(emb + (long long)tok * DD);
    const float4* p4 = (const float4*)(pos + (long long)t * DD);
    float4* x4 = (float4*)(x + (long long)row * DD);
    float4 a = e4[threadIdx.x];
    float4 p = p4[threadIdx.x];
    x4[threadIdx.x] = make_float4(a.x + p.x, a.y + p.y, a.z + p.z, a.w + p.w);
}

// ---------------------------------------------------------------------------
// LayerNorm: one block (256 threads) per row of D=1024
// ---------------------------------------------------------------------------
__global__ __launch_bounds__(256)
void layernorm_k(const float* __restrict__ x, const float* __restrict__ g,
                 const float* __restrict__ b, float* __restrict__ out)
{
    int row = blockIdx.x;
    int tid = threadIdx.x;
    const float4* x4 = (const float4*)(x + (long long)row * DD);
    float4 v = x4[tid];

    float s = v.x + v.y + v.z + v.w;
    #pragma unroll
    for (int o = 32; o; o >>= 1) s += __shfl_down(s, o);
    __shared__ float red[4];
    if ((tid & 63) == 0) red[tid >> 6] = s;
    __syncthreads();
    float mu = (red[0] + red[1] + red[2] + red[3]) * (1.0f / DD);

    float4 d = make_float4(v.x - mu, v.y - mu, v.z - mu, v.w - mu);
    float ss = d.x * d.x + d.y * d.y + d.z * d.z + d.w * d.w;
    #pragma unroll
    for (int o = 32; o; o >>= 1) ss += __shfl_down(ss, o);
    __syncthreads();                       // everyone done reading red (mu)
    if ((tid & 63) == 0) red[tid >> 6] = ss;
    __syncthreads();
    float var = (red[0] + red[1] + red[2] + red[3]) * (1.0f / DD);
    float rs = rsqrtf(var + 1e-5f);

    float4 gg = ((const float4*)g)[tid];
    float4 bb = ((const float4*)b)[tid];
    float4 o4;
    o4.x = d.x * rs * gg.x + bb.x;
    o4.y = d.y * rs * gg.y + bb.y;
    o4.z = d.z * rs * gg.z + bb.z;
    o4.w = d.w * rs * gg.w + bb.w;
    ((float4*)(out + (long long)row * DD))[tid] = o4;
}

// ---------------------------------------------------------------------------
// Causal softmax in place over rows of length T=1024.
// grid = B*H*T blocks; row index encodes t in low bits.
// ---------------------------------------------------------------------------
__global__ __launch_bounds__(256)
void softmax_causal_k(float* __restrict__ sc)
{
    long long row = blockIdx.x;
    int t = (int)(row & (TT - 1));
    float* p = sc + row * TT;
    int tid = threadIdx.x;
    float4 v = ((const float4*)p)[tid];
    float vals[4] = {v.x, v.y, v.z, v.w};
    int s0 = tid * 4;

    float m = -INFINITY;
    #pragma unroll
    for (int j = 0; j < 4; j++) if (s0 + j <= t) m = fmaxf(m, vals[j]);
    #pragma unroll
    for (int o = 32; o; o >>= 1) m = fmaxf(m, __shfl_down(m, o));
    __shared__ float red[4];
    if ((tid & 63) == 0) red[tid >> 6] = m;
    __syncthreads();
    float M = fmaxf(fmaxf(red[0], red[1]), fmaxf(red[2], red[3]));

    float e[4];
    float ssum = 0.f;
    #pragma unroll
    for (int j = 0; j < 4; j++) {
        e[j] = (s0 + j <= t) ? __expf(vals[j] - M) : 0.f;
        ssum += e[j];
    }
    #pragma unroll
    for (int o = 32; o; o >>= 1) ssum += __shfl_down(ssum, o);
    __syncthreads();
    if ((tid & 63) == 0) red[tid >> 6] = ssum;
    __syncthreads();
    float S = red[0] + red[1] + red[2] + red[3];
    float inv = 1.0f / S;
    ((float4*)p)[tid] = make_float4(e[0] * inv, e[1] * inv, e[2] * inv, e[3] * inv);
}

// ---------------------------------------------------------------------------
// Generic fp32 tiled GEMM. C = alpha*(A@B[^T]) [+bias] [+res] [relu]
// 64x64 tile, K-tile 16, 256 threads, 4x4 per thread.
// Batch via blockIdx.z: off = (z>>4)*s_hi + (z&15)*s_lo per operand.
// All M,N multiples of 64; K multiple of 16 (true for every call here).
// ---------------------------------------------------------------------------
#define TS 64
#define KT 16

template <bool TRANSB>
__global__ __launch_bounds__(256)
void gemm_f32(const float* __restrict__ A, const float* __restrict__ B,
              const float* __restrict__ bias, const float* __restrict__ res,
              float* __restrict__ C,
              int M, int N, int K, int lda, int ldb, int ldc,
              long long sAh, long long sAl, long long sBh, long long sBl,
              long long sCh, long long sCl,
              float alpha, int relu)
{
    __shared__ __align__(16) float As[KT][TS + 4];
    __shared__ __align__(16) float Bs[KT][TS + 4];

    int z = blockIdx.z;
    A += (long long)(z >> 4) * sAh + (long long)(z & 15) * sAl;
    B += (long long)(z >> 4) * sBh + (long long)(z & 15) * sBl;
    long long offC = (long long)(z >> 4) * sCh + (long long)(z & 15) * sCl;
    C += offC;
    if (res) res += offC;

    int tid = threadIdx.x;
    int tx = tid & 15;
    int ty = tid >> 4;
    int bm = blockIdx.y * TS;
    int bn = blockIdx.x * TS;

    float acc[4][4];
    #pragma unroll
    for (int i = 0; i < 4; i++)
        #pragma unroll
        for (int j = 0; j < 4; j++) acc[i][j] = 0.f;

    for (int k0 = 0; k0 < K; k0 += KT) {
        {   // A tile: As[k][m] <- A[(bm+m)*lda + k0+k]
            int k = tid & 15;
            int m = tid >> 4;
            #pragma unroll
            for (int i = 0; i < 4; i++)
                As[k][m + 16 * i] = A[(long long)(bm + m + 16 * i) * lda + k0 + k];
        }
        if (TRANSB) {   // Bs[k][n] <- B[(bn+n)*ldb + k0+k]
            int k = tid & 15;
            int n = tid >> 4;
            #pragma unroll
            for (int i = 0; i < 4; i++)
                Bs[k][n + 16 * i] = B[(long long)(bn + n + 16 * i) * ldb + k0 + k];
        } else {        // Bs[k][n] <- B[(k0+k)*ldb + bn+n]
            int n = tid & 63;
            int k = tid >> 6;
            #pragma unroll
            for (int i = 0; i < 4; i++)
                Bs[k + 4 * i][n] = B[(long long)(k0 + k + 4 * i) * ldb + bn + n];
        }
        __syncthreads();

        #pragma unroll
        for (int k = 0; k < KT; k++) {
            float4 a = *(const float4*)&As[k][ty * 4];
            float4 b = *(const float4*)&Bs[k][tx * 4];
            acc[0][0] += a.x * b.x; acc[0][1] += a.x * b.y;
            acc[0][2] += a.x * b.z; acc[0][3] += a.x * b.w;
            acc[1][0] += a.y * b.x; acc[1][1] += a.y * b.y;
            acc[1][2] += a.y * b.z; acc[1][3] += a.y * b.w;
            acc[2][0] += a.z * b.x; acc[2][1] += a.z * b.y;
            acc[2][2] += a.z * b.z; acc[2][3] += a.z * b.w;
            acc[3][0] += a.w * b.x; acc[3][1] += a.w * b.y;
            acc[3][2] += a.w * b.z; acc[3][3] += a.w * b.w;
        }
        __syncthreads();
    }

    #pragma unroll
    for (int i = 0; i < 4; i++) {
        int m = bm + ty * 4 + i;
        #pragma unroll
        for (int j = 0; j < 4; j++) {
            int n = bn + tx * 4 + j;
            float v = acc[i][j] * alpha;
            if (bias) v += bias[n];
            if (res) v += res[(long long)m * ldc + n];
            if (relu) v = fmaxf(v, 0.f);
            C[(long long)m * ldc + n] = v;
        }
    }
}

// ---------------------------------------------------------------------------
// Launcher
// ---------------------------------------------------------------------------
extern "C" void kernel_launch(void* const* d_in, const int* in_sizes, int n_in,
                              void* d_out, int out_size, void* d_ws, size_t ws_size,
                              hipStream_t stream)
{
    const int*   idx   = (const int*)  d_in[0];
    const float* emb   = (const float*)d_in[1];
    const float* pos   = (const float*)d_in[2];
    const float* wq    = (const float*)d_in[3];   // [L,H,D,DH]
    const float* wk    = (const float*)d_in[4];
    const float* wv    = (const float*)d_in[5];
    const float* wo    = (const float*)d_in[6];   // [L,D,D]
    const float* w1    = (const float*)d_in[7];   // [L,D,HID]
    const float* b1    = (const float*)d_in[8];   // [L,HID]
    const float* w2    = (const float*)d_in[9];   // [L,HID,D]
    const float* b2    = (const float*)d_in[10];  // [L,D]
    const float* ln1_g = (const float*)d_in[11];
    const float* ln1_b = (const float*)d_in[12];
    const float* ln2_g = (const float*)d_in[13];
    const float* ln2_b = (const float*)d_in[14];
    const float* lnf_g = (const float*)d_in[15];
    const float* lnf_b = (const float*)d_in[16];
    float* out = (float*)d_out;

    const long long NTOK = (long long)BB * TT;        // 2048
    const long long SZ_X = NTOK * DD;                 // 2M floats

    float* x     = (float*)d_ws;
    float* h     = x    + SZ_X;
    float* q     = h    + SZ_X;
    float* k     = q    + SZ_X;   // [B,H,T,DH] = 2M
    float* v     = k    + SZ_X;
    float* attn  = v    + SZ_X;   // [B,T,D]
    float* ffhid = attn + SZ_X;   // [B,T,HID] = 8M floats
    float* sc    = out;           // scores [B,H,T,T] = 33.5M floats, d_out as scratch

    const long long sTD   = (long long)TT * DD;       // per-b stride in x/h
    const long long sHead = (long long)TT * DHD;      // per-(b,h) stride in q/k/v
    const long long sHTDH = (long long)HH * sHead;    // per-b stride in q/k/v
    const long long sTT   = (long long)TT * TT;       // per-(b,h) stride in scores
    const long long sHTT  = (long long)HH * sTT;

    // x = emb[idx] + pos
    embed_k<<<dim3((unsigned)NTOK), 256, 0, stream>>>(idx, emb, pos, x);

    for (int l = 0; l < LL; l++) {
        const float* wq_l = wq + (long long)l * HH * DD * DHD;
        const float* wk_l = wk + (long long)l * HH * DD * DHD;
        const float* wv_l = wv + (long long)l * HH * DD * DHD;
        const float* wo_l = wo + (long long)l * DD * DD;
        const float* w1_l = w1 + (long long)l * DD * HID;
        const float* w2_l = w2 + (long long)l * HID * DD;

        // h = LN1(x)
        layernorm_k<<<dim3((unsigned)NTOK), 256, 0, stream>>>(
            x, ln1_g + l * DD, ln1_b + l * DD, h);

        // q/k/v[b,h] = h[b] @ w{q,k,v}[l,h]   (M=T, N=DH, K=D), z = b*16+h
        dim3 gqkv(1, TT / TS, BB * HH);
        gemm_f32<false><<<gqkv, 256, 0, stream>>>(h, wq_l, nullptr, nullptr, q,
            TT, DHD, DD, DD, DHD, DHD,
            sTD, 0, 0, (long long)DD * DHD, sHTDH, sHead, 1.0f, 0);
        gemm_f32<false><<<gqkv, 256, 0, stream>>>(h, wk_l, nullptr, nullptr, k,
            TT, DHD, DD, DD, DHD, DHD,
            sTD, 0, 0, (long long)DD * DHD, sHTDH, sHead, 1.0f, 0);
        gemm_f32<false><<<gqkv, 256, 0, stream>>>(h, wv_l, nullptr, nullptr, v,
            TT, DHD, DD, DD, DHD, DHD,
            sTD, 0, 0, (long long)DD * DHD, sHTDH, sHead, 1.0f, 0);

        // scores[b,h] = (q[b,h] @ k[b,h]^T) * 1/sqrt(DH)
        dim3 gsc(TT / TS, TT / TS, BB * HH);
        gemm_f32<true><<<gsc, 256, 0, stream>>>(q, k, nullptr, nullptr, sc,
            TT, TT, DHD, DHD, DHD, TT,
            sHTDH, sHead, sHTDH, sHead, sHTT, sTT, 0.125f, 0);

        // causal softmax in place
        softmax_causal_k<<<dim3((unsigned)(BB * HH * TT)), 256, 0, stream>>>(sc);

        // attn[b, :, h*DH:(h+1)*DH] = scores[b,h] @ v[b,h]
        dim3 go(1, TT / TS, BB * HH);
        gemm_f32<false><<<go, 256, 0, stream>>>(sc, v, nullptr, nullptr, attn,
            TT, DHD, TT, TT, DHD, DD,
            sHTT, sTT, sHTDH, sHead, sTD, DHD, 1.0f, 0);

        // x = x + attn @ wo^T
        dim3 gp(DD / TS, (unsigned)(NTOK / TS), 1);
        gemm_f32<true><<<gp, 256, 0, stream>>>(attn, wo_l, nullptr, x, x,
            (int)NTOK, DD, DD, DD, DD, DD,
            0, 0, 0, 0, 0, 0, 1.0f, 0);

        // h = LN2(x)
        layernorm_k<<<dim3((unsigned)NTOK), 256, 0, stream>>>(
            x, ln2_g + l * DD, ln2_b + l * DD, h);

        // ffhid = relu(h @ w1 + b1)
        dim3 gf1(HID / TS, (unsigned)(NTOK / TS), 1);
        gemm_f32<false><<<gf1, 256, 0, stream>>>(h, w1_l, b1 + (long long)l * HID,
            nullptr, ffhid,
            (int)NTOK, HID, DD, DD, HID, HID,
            0, 0, 0, 0, 0, 0, 1.0f, 1);

        // x = x + ffhid @ w2 + b2
        dim3 gf2(DD / TS, (unsigned)(NTOK / TS), 1);
        gemm_f32<false><<<gf2, 256, 0, stream>>>(ffhid, w2_l, b2 + (long long)l * DD,
            x, x,
            (int)NTOK, DD, HID, HID, DD, DD,
            0, 0, 0, 0, 0, 0, 1.0f, 0);
    }

    // h = LNf(x)
    layernorm_k<<<dim3((unsigned)NTOK), 256, 0, stream>>>(x, lnf_g, lnf_b, h);

    // logits = h @ emb^T  (M=2048, N=32000, K=1024)
    dim3 gl(VV / TS, (unsigned)(NTOK / TS), 1);
    gemm_f32<true><<<gl, 256, 0, stream>>>(h, emb, nullptr, nullptr, out,
        (int)NTOK, VV, DD, DD, DD, VV,
        0, 0, 0, 0, 0, 0, 1.0f, 0);
}